// Round 4
// baseline (665.239 us; speedup 1.0000x reference)
//
#include <hip/hip_runtime.h>

#define N_SRC 100000
#define N_DST 20000
#define NE 640000
#define IN_F 256
#define NH 4
#define DF 32
#define NCOL 128  /* NH*DF */
#define LP 132    /* padded LDS row length (floats) */
#define MAXE 256  /* cached edges per dst in k_fused */

// ---------------- K0: fold attn vectors into W (fp64) ----------------
__global__ void k_prep(const float* __restrict__ W,
                       const float* __restrict__ attn_l,
                       const float* __restrict__ attn_r,
                       double* __restrict__ Wlr) {
    int k = threadIdx.x;  // 256 threads, one per k
    for (int j = 0; j < 8; ++j) {
        const float* attn = (j < 4) ? attn_l : attn_r;
        int hh = j & 3;
        double s = 0.0;
        for (int d = 0; d < DF; ++d)
            s += (double)W[k * NCOL + hh * DF + d] * (double)attn[hh * DF + d];
        Wlr[k * 8 + j] = s;
    }
}

// ---------------- K1: h = x @ W (fp32), 128x128 tile, kb=32 ----------------
__global__ __launch_bounds__(256, 4) void k_gemm(const float* __restrict__ x,
                                                 const float* __restrict__ W,
                                                 float* __restrict__ h) {
    __shared__ float xT[32][LP];  // transposed x tile: xT[k][row]
    __shared__ float wt[32][LP];  // W tile: wt[k][col]
    const int tid = threadIdx.x;
    const int row0 = blockIdx.x * 128;
    const int cg = tid & 15;   // col group: cols cg*4..+3 and 64+cg*4..+3
    const int rg = tid >> 4;   // row group: rows rg*8..+7
    const int r0 = rg * 8;
    const int c0 = cg * 4;

    float acc0[8][4], acc1[8][4];
#pragma unroll
    for (int j = 0; j < 8; ++j)
#pragma unroll
        for (int m = 0; m < 4; ++m) { acc0[j][m] = 0.f; acc1[j][m] = 0.f; }

    for (int kc = 0; kc < IN_F; kc += 32) {
        // stage x tile (transposed): 128 rows x 32 k
#pragma unroll
        for (int it = 0; it < 4; ++it) {
            int i = it * 256 + tid;
            int row = i >> 3;   // 0..127
            int q = i & 7;      // k-quad
            float4 v = make_float4(0.f, 0.f, 0.f, 0.f);
            if (row0 + row < N_SRC)
                v = *((const float4*)(x + (size_t)(row0 + row) * IN_F + kc + q * 4));
            xT[q * 4 + 0][row] = v.x;
            xT[q * 4 + 1][row] = v.y;
            xT[q * 4 + 2][row] = v.z;
            xT[q * 4 + 3][row] = v.w;
        }
        // stage W tile: 32 k x 128 cols
#pragma unroll
        for (int it = 0; it < 4; ++it) {
            int i = it * 256 + tid;
            int kk = i >> 5;    // 0..31
            int cq = i & 31;    // col quad
            float4 v = *((const float4*)(W + (size_t)(kc + kk) * NCOL + cq * 4));
            *((float4*)&wt[kk][cq * 4]) = v;
        }
        __syncthreads();
#pragma unroll
        for (int k = 0; k < 32; ++k) {
            float4 xa = *((const float4*)&xT[k][r0]);
            float4 xb = *((const float4*)&xT[k][r0 + 4]);
            float4 wa = *((const float4*)&wt[k][c0]);
            float4 wb = *((const float4*)&wt[k][64 + c0]);
            float xr[8] = {xa.x, xa.y, xa.z, xa.w, xb.x, xb.y, xb.z, xb.w};
            float w0[4] = {wa.x, wa.y, wa.z, wa.w};
            float w1[4] = {wb.x, wb.y, wb.z, wb.w};
#pragma unroll
            for (int j = 0; j < 8; ++j)
#pragma unroll
                for (int m = 0; m < 4; ++m) {
                    acc0[j][m] += xr[j] * w0[m];
                    acc1[j][m] += xr[j] * w1[m];
                }
        }
        __syncthreads();
    }
#pragma unroll
    for (int j = 0; j < 8; ++j) {
        int row = row0 + r0 + j;
        if (row < N_SRC) {
            *((float4*)(h + (size_t)row * NCOL + c0)) =
                make_float4(acc0[j][0], acc0[j][1], acc0[j][2], acc0[j][3]);
            *((float4*)(h + (size_t)row * NCOL + 64 + c0)) =
                make_float4(acc1[j][0], acc1[j][1], acc1[j][2], acc1[j][3]);
        }
    }
}

// ---------------- K2: el / er_src via fp64 dot(x_row, Wlr) ----------------
__global__ __launch_bounds__(256) void k_scores(const float* __restrict__ x,
                                                const double* __restrict__ Wlr,
                                                double* __restrict__ el,
                                                double* __restrict__ er_src) {
    const int lane = threadIdx.x & 63;
    const int wid = (blockIdx.x * 256 + threadIdx.x) >> 6;
    const int nwaves = gridDim.x * 4;

    double wreg[4][8];
#pragma unroll
    for (int i = 0; i < 4; ++i)
#pragma unroll
        for (int j = 0; j < 8; ++j)
            wreg[i][j] = Wlr[(lane * 4 + i) * 8 + j];

    for (int row = wid; row < N_SRC; row += nwaves) {
        float4 xv = *((const float4*)(x + (size_t)row * IN_F + lane * 4));
        double acc[8];
#pragma unroll
        for (int j = 0; j < 8; ++j) acc[j] = 0.0;
        const double xd[4] = {(double)xv.x, (double)xv.y, (double)xv.z, (double)xv.w};
#pragma unroll
        for (int i = 0; i < 4; ++i)
#pragma unroll
            for (int j = 0; j < 8; ++j)
                acc[j] += xd[i] * wreg[i][j];
#pragma unroll
        for (int j = 0; j < 8; ++j) {
#pragma unroll
            for (int m = 32; m >= 1; m >>= 1)
                acc[j] += __shfl_xor(acc[j], m);
        }
        if (lane == 0) {
#pragma unroll
            for (int hh = 0; hh < 4; ++hh) {
                el[(size_t)row * NH + hh] = acc[hh];
                er_src[(size_t)row * NH + hh] = acc[4 + hh];
            }
        }
    }
}

// ---------------- K3: gather er for dst nodes ----------------
__global__ __launch_bounds__(256) void k_gather(const int* __restrict__ dst_to_src,
                                                const double* __restrict__ er_src,
                                                double* __restrict__ er_dst) {
    int gid = blockIdx.x * 256 + threadIdx.x;
    if (gid >= N_DST * NH) return;
    int nd = gid >> 2, hh = gid & 3;
    er_dst[gid] = er_src[(size_t)dst_to_src[nd] * NH + hh];
}

// ---------------- CSR build ----------------
__global__ __launch_bounds__(256) void k_hist(const int* __restrict__ dst_idx,
                                              int* __restrict__ cnt) {
    int gid = blockIdx.x * 256 + threadIdx.x;
    if (gid >= NE) return;
    atomicAdd(cnt + dst_idx[gid], 1);
}

__global__ __launch_bounds__(1024) void k_scan(const int* __restrict__ cnt,
                                               int* __restrict__ offsets) {
    __shared__ int wsum[16];
    __shared__ int carry;
    int tid = threadIdx.x, lane = tid & 63, w = tid >> 6;
    if (tid == 0) carry = 0;
    __syncthreads();
    for (int base = 0; base < N_DST; base += 1024) {
        int i = base + tid;
        int v = (i < N_DST) ? cnt[i] : 0;
        int s = v;
#pragma unroll
        for (int off = 1; off < 64; off <<= 1) {
            int t = __shfl_up(s, off);
            if (lane >= off) s += t;
        }
        if (lane == 63) wsum[w] = s;
        __syncthreads();
        int wprefix = 0;
        for (int k = 0; k < w; ++k) wprefix += wsum[k];
        int incl = s + wprefix + carry;
        if (i < N_DST) offsets[i + 1] = incl;
        __syncthreads();
        if (tid == 1023) carry = incl;
        __syncthreads();
    }
    if (tid == 0) offsets[0] = 0;
}

__global__ __launch_bounds__(256) void k_fill(const int* __restrict__ src_idx,
                                              const int* __restrict__ dst_idx,
                                              const int* __restrict__ offsets,
                                              int* __restrict__ cursor,
                                              int* __restrict__ edge_src) {
    int gid = blockIdx.x * 256 + threadIdx.x;
    if (gid >= NE) return;
    int d = dst_idx[gid];
    int pos = offsets[d] + atomicAdd(cursor + d, 1);
    edge_src[pos] = src_idx[gid];
}

// ---------------- K5: fused segment-sum + normalize + weighted gather ----------------
// one block (128 threads) per dst node
__global__ __launch_bounds__(128) void k_fused(const int* __restrict__ offsets,
                                               const int* __restrict__ edge_src,
                                               const double* __restrict__ el,
                                               const double* __restrict__ er_dst,
                                               const float* __restrict__ h,
                                               float* __restrict__ out) {
    const int d = blockIdx.x;
    const int tid = threadIdx.x;
    const int beg = offsets[d];
    const int deg = offsets[d + 1] - beg;

    __shared__ double e_lds[MAXE][NH];  // 8 KB
    __shared__ int s_lds[MAXE];         // 1 KB
    __shared__ double red[128][NH];     // 4 KB
    __shared__ double S_sh[NH];
    __shared__ double facc[4][32][4];   // 4 KB

    double er4[NH];
#pragma unroll
    for (int hh = 0; hh < NH; ++hh) er4[hh] = er_dst[(size_t)d * NH + hh];

    // phase 1: per-edge scores, cache in LDS, block-sum S
    double sum4[NH] = {0.0, 0.0, 0.0, 0.0};
    for (int j = tid; j < deg; j += 128) {
        int s = edge_src[beg + j];
        if (j < MAXE) s_lds[j] = s;
        const double* elp = el + (size_t)s * NH;
#pragma unroll
        for (int hh = 0; hh < NH; ++hh) {
            double e = elp[hh] + er4[hh];
            e = (e >= 0.0) ? e : 0.2 * e;
            if (j < MAXE) e_lds[j][hh] = e;
            sum4[hh] += e;
        }
    }
#pragma unroll
    for (int hh = 0; hh < NH; ++hh) red[tid][hh] = sum4[hh];
    __syncthreads();
    for (int off = 64; off >= 1; off >>= 1) {
        if (tid < off) {
#pragma unroll
            for (int hh = 0; hh < NH; ++hh) red[tid][hh] += red[tid + off][hh];
        }
        __syncthreads();
    }
    if (tid < NH) S_sh[tid] = red[0][tid];
    __syncthreads();

    // phase 2: 4 edges in flight; thread = (edge sublane js, col quad cq)
    const int js = tid >> 5;
    const int cq = tid & 31;
    const int hd = cq >> 3;  // head for cols cq*4..cq*4+3
    const double Sinv = (deg > 0) ? 1.0 / S_sh[hd] : 0.0;

    double acc[4] = {0.0, 0.0, 0.0, 0.0};
    for (int j = js; j < deg; j += 4) {
        int s;
        double e;
        if (j < MAXE) {
            s = s_lds[j];
            e = e_lds[j][hd];
        } else {
            s = edge_src[beg + j];
            e = el[(size_t)s * NH + hd] + er4[hd];
            e = (e >= 0.0) ? e : 0.2 * e;
        }
        double att = e * Sinv;
        float4 hv = *((const float4*)(h + (size_t)s * NCOL + cq * 4));
        acc[0] += att * (double)hv.x;
        acc[1] += att * (double)hv.y;
        acc[2] += att * (double)hv.z;
        acc[3] += att * (double)hv.w;
    }
#pragma unroll
    for (int m = 0; m < 4; ++m) facc[js][cq][m] = acc[m];
    __syncthreads();
    if (tid < 32) {
        float4 o;
        o.x = (float)(facc[0][tid][0] + facc[1][tid][0] + facc[2][tid][0] + facc[3][tid][0]);
        o.y = (float)(facc[0][tid][1] + facc[1][tid][1] + facc[2][tid][1] + facc[3][tid][1]);
        o.z = (float)(facc[0][tid][2] + facc[1][tid][2] + facc[2][tid][2] + facc[3][tid][2]);
        o.w = (float)(facc[0][tid][3] + facc[1][tid][3] + facc[2][tid][3] + facc[3][tid][3]);
        *((float4*)(out + (size_t)d * NCOL + tid * 4)) = o;
    }
}

extern "C" void kernel_launch(void* const* d_in, const int* in_sizes, int n_in,
                              void* d_out, int out_size, void* d_ws, size_t ws_size,
                              hipStream_t stream) {
    const float* x      = (const float*)d_in[0];
    const float* W      = (const float*)d_in[1];
    const float* attn_l = (const float*)d_in[2];
    const float* attn_r = (const float*)d_in[3];
    const int* src_idx  = (const int*)d_in[4];
    const int* dst_idx  = (const int*)d_in[5];
    const int* dst_to_src = (const int*)d_in[6];
    float* out = (float*)d_out;

    char* p = (char*)d_ws;
    double* Wlr    = (double*)p;  p += (size_t)IN_F * 8 * sizeof(double);
    double* el     = (double*)p;  p += (size_t)N_SRC * NH * sizeof(double);
    double* er_src = (double*)p;  p += (size_t)N_SRC * NH * sizeof(double);
    double* er_dst = (double*)p;  p += (size_t)N_DST * NH * sizeof(double);
    float*  h      = (float*)p;   p += (size_t)N_SRC * NCOL * sizeof(float);
    int*    cnt      = (int*)p;   p += (size_t)N_DST * sizeof(int);
    int*    offsets  = (int*)p;   p += (size_t)(N_DST + 1) * sizeof(int);
    int*    cursor   = (int*)p;   p += (size_t)N_DST * sizeof(int);
    int*    edge_src = (int*)p;   p += (size_t)NE * sizeof(int);

    hipMemsetAsync(cnt, 0, (size_t)N_DST * sizeof(int), stream);
    hipMemsetAsync(cursor, 0, (size_t)N_DST * sizeof(int), stream);

    k_prep<<<1, IN_F, 0, stream>>>(W, attn_l, attn_r, Wlr);
    k_gemm<<<(N_SRC + 127) / 128, 256, 0, stream>>>(x, W, h);
    k_scores<<<512, 256, 0, stream>>>(x, Wlr, el, er_src);
    k_gather<<<(N_DST * NH + 255) / 256, 256, 0, stream>>>(dst_to_src, er_src, er_dst);
    k_hist<<<(NE + 255) / 256, 256, 0, stream>>>(dst_idx, cnt);
    k_scan<<<1, 1024, 0, stream>>>(cnt, offsets);
    k_fill<<<(NE + 255) / 256, 256, 0, stream>>>(src_idx, dst_idx, offsets, cursor, edge_src);
    k_fused<<<N_DST, 128, 0, stream>>>(offsets, edge_src, el, er_dst, h, out);
}

// Round 5
// 450.049 us; speedup vs baseline: 1.4781x; 1.4781x over previous
//
#include <hip/hip_runtime.h>

#define N_SRC 100000
#define N_DST 20000
#define NE 640000
#define IN_F 256
#define NH 4
#define DF 32
#define NCOL 128  /* NH*DF */
#define LP 132    /* padded LDS row length (floats) */
#define MAXE 256  /* cached edges per dst in k_fused */

// ---------------- K0: fold attn vectors into W (fp64) ----------------
__global__ void k_prep(const float* __restrict__ W,
                       const float* __restrict__ attn_l,
                       const float* __restrict__ attn_r,
                       double* __restrict__ Wlr) {
    int k = threadIdx.x;  // 256 threads, one per k
    for (int j = 0; j < 8; ++j) {
        const float* attn = (j < 4) ? attn_l : attn_r;
        int hh = j & 3;
        double s = 0.0;
        for (int d = 0; d < DF; ++d)
            s += (double)W[k * NCOL + hh * DF + d] * (double)attn[hh * DF + d];
        Wlr[k * 8 + j] = s;
    }
}

// ---------------- K1: h = x @ W (fp32), 128x128 tile, kb=32 ----------------
// NOTE: no min-waves clause — round-4's (256,4) capped VGPRs at 64 and the
// 64 accumulators spilled to scratch (815 MB WRITE_SIZE). Let VGPRs float.
__global__ __launch_bounds__(256) void k_gemm(const float* __restrict__ x,
                                              const float* __restrict__ W,
                                              float* __restrict__ h) {
    __shared__ float xT[32][LP];  // transposed x tile: xT[k][row]
    __shared__ float wt[32][LP];  // W tile: wt[k][col]
    const int tid = threadIdx.x;
    const int row0 = blockIdx.x * 128;
    const int cg = tid & 15;   // col group: cols cg*4..+3 and 64+cg*4..+3
    const int rg = tid >> 4;   // row group: rows rg*8..+7
    const int r0 = rg * 8;
    const int c0 = cg * 4;

    float acc0[8][4], acc1[8][4];
#pragma unroll
    for (int j = 0; j < 8; ++j)
#pragma unroll
        for (int m = 0; m < 4; ++m) { acc0[j][m] = 0.f; acc1[j][m] = 0.f; }

    for (int kc = 0; kc < IN_F; kc += 32) {
        // stage x tile (transposed): 128 rows x 32 k
#pragma unroll
        for (int it = 0; it < 4; ++it) {
            int i = it * 256 + tid;
            int row = i >> 3;   // 0..127
            int q = i & 7;      // k-quad
            float4 v = make_float4(0.f, 0.f, 0.f, 0.f);
            if (row0 + row < N_SRC)
                v = *((const float4*)(x + (size_t)(row0 + row) * IN_F + kc + q * 4));
            xT[q * 4 + 0][row] = v.x;
            xT[q * 4 + 1][row] = v.y;
            xT[q * 4 + 2][row] = v.z;
            xT[q * 4 + 3][row] = v.w;
        }
        // stage W tile: 32 k x 128 cols
#pragma unroll
        for (int it = 0; it < 4; ++it) {
            int i = it * 256 + tid;
            int kk = i >> 5;    // 0..31
            int cq = i & 31;    // col quad
            float4 v = *((const float4*)(W + (size_t)(kc + kk) * NCOL + cq * 4));
            *((float4*)&wt[kk][cq * 4]) = v;
        }
        __syncthreads();
#pragma unroll
        for (int k = 0; k < 32; ++k) {
            float4 xa = *((const float4*)&xT[k][r0]);
            float4 xb = *((const float4*)&xT[k][r0 + 4]);
            float4 wa = *((const float4*)&wt[k][c0]);
            float4 wb = *((const float4*)&wt[k][64 + c0]);
            float xr[8] = {xa.x, xa.y, xa.z, xa.w, xb.x, xb.y, xb.z, xb.w};
            float w0[4] = {wa.x, wa.y, wa.z, wa.w};
            float w1[4] = {wb.x, wb.y, wb.z, wb.w};
#pragma unroll
            for (int j = 0; j < 8; ++j)
#pragma unroll
                for (int m = 0; m < 4; ++m) {
                    acc0[j][m] += xr[j] * w0[m];
                    acc1[j][m] += xr[j] * w1[m];
                }
        }
        __syncthreads();
    }
#pragma unroll
    for (int j = 0; j < 8; ++j) {
        int row = row0 + r0 + j;
        if (row < N_SRC) {
            *((float4*)(h + (size_t)row * NCOL + c0)) =
                make_float4(acc0[j][0], acc0[j][1], acc0[j][2], acc0[j][3]);
            *((float4*)(h + (size_t)row * NCOL + 64 + c0)) =
                make_float4(acc1[j][0], acc1[j][1], acc1[j][2], acc1[j][3]);
        }
    }
}

// ---------------- K2: el / er_src via fp64 dot(x_row, Wlr) ----------------
__global__ __launch_bounds__(256) void k_scores(const float* __restrict__ x,
                                                const double* __restrict__ Wlr,
                                                double* __restrict__ el,
                                                double* __restrict__ er_src) {
    const int lane = threadIdx.x & 63;
    const int wid = (blockIdx.x * 256 + threadIdx.x) >> 6;
    const int nwaves = gridDim.x * 4;

    double wreg[4][8];
#pragma unroll
    for (int i = 0; i < 4; ++i)
#pragma unroll
        for (int j = 0; j < 8; ++j)
            wreg[i][j] = Wlr[(lane * 4 + i) * 8 + j];

    for (int row = wid; row < N_SRC; row += nwaves) {
        float4 xv = *((const float4*)(x + (size_t)row * IN_F + lane * 4));
        double acc[8];
#pragma unroll
        for (int j = 0; j < 8; ++j) acc[j] = 0.0;
        const double xd[4] = {(double)xv.x, (double)xv.y, (double)xv.z, (double)xv.w};
#pragma unroll
        for (int i = 0; i < 4; ++i)
#pragma unroll
            for (int j = 0; j < 8; ++j)
                acc[j] += xd[i] * wreg[i][j];
#pragma unroll
        for (int j = 0; j < 8; ++j) {
#pragma unroll
            for (int m = 32; m >= 1; m >>= 1)
                acc[j] += __shfl_xor(acc[j], m);
        }
        if (lane == 0) {
#pragma unroll
            for (int hh = 0; hh < 4; ++hh) {
                el[(size_t)row * NH + hh] = acc[hh];
                er_src[(size_t)row * NH + hh] = acc[4 + hh];
            }
        }
    }
}

// ---------------- K3: gather er for dst nodes ----------------
__global__ __launch_bounds__(256) void k_gather(const int* __restrict__ dst_to_src,
                                                const double* __restrict__ er_src,
                                                double* __restrict__ er_dst) {
    int gid = blockIdx.x * 256 + threadIdx.x;
    if (gid >= N_DST * NH) return;
    int nd = gid >> 2, hh = gid & 3;
    er_dst[gid] = er_src[(size_t)dst_to_src[nd] * NH + hh];
}

// ---------------- CSR build ----------------
__global__ __launch_bounds__(256) void k_hist(const int* __restrict__ dst_idx,
                                              int* __restrict__ cnt) {
    int gid = blockIdx.x * 256 + threadIdx.x;
    if (gid >= NE) return;
    atomicAdd(cnt + dst_idx[gid], 1);
}

__global__ __launch_bounds__(1024) void k_scan(const int* __restrict__ cnt,
                                               int* __restrict__ offsets) {
    __shared__ int wsum[16];
    __shared__ int carry;
    int tid = threadIdx.x, lane = tid & 63, w = tid >> 6;
    if (tid == 0) carry = 0;
    __syncthreads();
    for (int base = 0; base < N_DST; base += 1024) {
        int i = base + tid;
        int v = (i < N_DST) ? cnt[i] : 0;
        int s = v;
#pragma unroll
        for (int off = 1; off < 64; off <<= 1) {
            int t = __shfl_up(s, off);
            if (lane >= off) s += t;
        }
        if (lane == 63) wsum[w] = s;
        __syncthreads();
        int wprefix = 0;
        for (int k = 0; k < w; ++k) wprefix += wsum[k];
        int incl = s + wprefix + carry;
        if (i < N_DST) offsets[i + 1] = incl;
        __syncthreads();
        if (tid == 1023) carry = incl;
        __syncthreads();
    }
    if (tid == 0) offsets[0] = 0;
}

__global__ __launch_bounds__(256) void k_fill(const int* __restrict__ src_idx,
                                              const int* __restrict__ dst_idx,
                                              const int* __restrict__ offsets,
                                              int* __restrict__ cursor,
                                              int* __restrict__ edge_src) {
    int gid = blockIdx.x * 256 + threadIdx.x;
    if (gid >= NE) return;
    int d = dst_idx[gid];
    int pos = offsets[d] + atomicAdd(cursor + d, 1);
    edge_src[pos] = src_idx[gid];
}

// ---------------- K5: fused segment-sum + normalize + weighted gather ----------------
// one block (128 threads) per dst node
__global__ __launch_bounds__(128) void k_fused(const int* __restrict__ offsets,
                                               const int* __restrict__ edge_src,
                                               const double* __restrict__ el,
                                               const double* __restrict__ er_dst,
                                               const float* __restrict__ h,
                                               float* __restrict__ out) {
    const int d = blockIdx.x;
    const int tid = threadIdx.x;
    const int beg = offsets[d];
    const int deg = offsets[d + 1] - beg;

    __shared__ double e_lds[MAXE][NH];  // 8 KB
    __shared__ int s_lds[MAXE];         // 1 KB
    __shared__ double red[128][NH];     // 4 KB
    __shared__ double S_sh[NH];
    __shared__ double facc[4][32][4];   // 4 KB

    double er4[NH];
#pragma unroll
    for (int hh = 0; hh < NH; ++hh) er4[hh] = er_dst[(size_t)d * NH + hh];

    // phase 1: per-edge scores, cache in LDS, block-sum S
    double sum4[NH] = {0.0, 0.0, 0.0, 0.0};
    for (int j = tid; j < deg; j += 128) {
        int s = edge_src[beg + j];
        if (j < MAXE) s_lds[j] = s;
        const double* elp = el + (size_t)s * NH;
#pragma unroll
        for (int hh = 0; hh < NH; ++hh) {
            double e = elp[hh] + er4[hh];
            e = (e >= 0.0) ? e : 0.2 * e;
            if (j < MAXE) e_lds[j][hh] = e;
            sum4[hh] += e;
        }
    }
#pragma unroll
    for (int hh = 0; hh < NH; ++hh) red[tid][hh] = sum4[hh];
    __syncthreads();
    for (int off = 64; off >= 1; off >>= 1) {
        if (tid < off) {
#pragma unroll
            for (int hh = 0; hh < NH; ++hh) red[tid][hh] += red[tid + off][hh];
        }
        __syncthreads();
    }
    if (tid < NH) S_sh[tid] = red[0][tid];
    __syncthreads();

    // phase 2: 4 edges in flight; thread = (edge sublane js, col quad cq)
    const int js = tid >> 5;
    const int cq = tid & 31;
    const int hd = cq >> 3;  // head for cols cq*4..cq*4+3
    const double Sinv = (deg > 0) ? 1.0 / S_sh[hd] : 0.0;

    double acc[4] = {0.0, 0.0, 0.0, 0.0};
    for (int j = js; j < deg; j += 4) {
        int s;
        double e;
        if (j < MAXE) {
            s = s_lds[j];
            e = e_lds[j][hd];
        } else {
            s = edge_src[beg + j];
            e = el[(size_t)s * NH + hd] + er4[hd];
            e = (e >= 0.0) ? e : 0.2 * e;
        }
        double att = e * Sinv;
        float4 hv = *((const float4*)(h + (size_t)s * NCOL + cq * 4));
        acc[0] += att * (double)hv.x;
        acc[1] += att * (double)hv.y;
        acc[2] += att * (double)hv.z;
        acc[3] += att * (double)hv.w;
    }
#pragma unroll
    for (int m = 0; m < 4; ++m) facc[js][cq][m] = acc[m];
    __syncthreads();
    if (tid < 32) {
        float4 o;
        o.x = (float)(facc[0][tid][0] + facc[1][tid][0] + facc[2][tid][0] + facc[3][tid][0]);
        o.y = (float)(facc[0][tid][1] + facc[1][tid][1] + facc[2][tid][1] + facc[3][tid][1]);
        o.z = (float)(facc[0][tid][2] + facc[1][tid][2] + facc[2][tid][2] + facc[3][tid][2]);
        o.w = (float)(facc[0][tid][3] + facc[1][tid][3] + facc[2][tid][3] + facc[3][tid][3]);
        *((float4*)(out + (size_t)d * NCOL + tid * 4)) = o;
    }
}

extern "C" void kernel_launch(void* const* d_in, const int* in_sizes, int n_in,
                              void* d_out, int out_size, void* d_ws, size_t ws_size,
                              hipStream_t stream) {
    const float* x      = (const float*)d_in[0];
    const float* W      = (const float*)d_in[1];
    const float* attn_l = (const float*)d_in[2];
    const float* attn_r = (const float*)d_in[3];
    const int* src_idx  = (const int*)d_in[4];
    const int* dst_idx  = (const int*)d_in[5];
    const int* dst_to_src = (const int*)d_in[6];
    float* out = (float*)d_out;

    char* p = (char*)d_ws;
    double* Wlr    = (double*)p;  p += (size_t)IN_F * 8 * sizeof(double);
    double* el     = (double*)p;  p += (size_t)N_SRC * NH * sizeof(double);
    double* er_src = (double*)p;  p += (size_t)N_SRC * NH * sizeof(double);
    double* er_dst = (double*)p;  p += (size_t)N_DST * NH * sizeof(double);
    float*  h      = (float*)p;   p += (size_t)N_SRC * NCOL * sizeof(float);
    int*    cnt      = (int*)p;   p += (size_t)N_DST * sizeof(int);
    int*    offsets  = (int*)p;   p += (size_t)(N_DST + 1) * sizeof(int);
    int*    cursor   = (int*)p;   p += (size_t)N_DST * sizeof(int);
    int*    edge_src = (int*)p;   p += (size_t)NE * sizeof(int);

    hipMemsetAsync(cnt, 0, (size_t)N_DST * sizeof(int), stream);
    hipMemsetAsync(cursor, 0, (size_t)N_DST * sizeof(int), stream);

    k_prep<<<1, IN_F, 0, stream>>>(W, attn_l, attn_r, Wlr);
    k_gemm<<<(N_SRC + 127) / 128, 256, 0, stream>>>(x, W, h);
    k_scores<<<512, 256, 0, stream>>>(x, Wlr, el, er_src);
    k_gather<<<(N_DST * NH + 255) / 256, 256, 0, stream>>>(dst_to_src, er_src, er_dst);
    k_hist<<<(NE + 255) / 256, 256, 0, stream>>>(dst_idx, cnt);
    k_scan<<<1, 1024, 0, stream>>>(cnt, offsets);
    k_fill<<<(NE + 255) / 256, 256, 0, stream>>>(src_idx, dst_idx, offsets, cursor, edge_src);
    k_fused<<<N_DST, 128, 0, stream>>>(offsets, edge_src, el, er_dst, h, out);
}

// Round 6
// 410.503 us; speedup vs baseline: 1.6205x; 1.0963x over previous
//
#include <hip/hip_runtime.h>

#define N_SRC 100000
#define N_DST 20000
#define NE 640000
#define IN_F 256
#define NH 4
#define DF 32
#define NCOL 128  /* NH*DF */
#define MAXE 256  /* cached edges per dst in k_fused */

// ---------------- K0: fold attn vectors into W (fp64) ----------------
__global__ void k_prep(const float* __restrict__ W,
                       const float* __restrict__ attn_l,
                       const float* __restrict__ attn_r,
                       double* __restrict__ Wlr) {
    int k = threadIdx.x;  // 256 threads, one per k
    for (int j = 0; j < 8; ++j) {
        const float* attn = (j < 4) ? attn_l : attn_r;
        int hh = j & 3;
        double s = 0.0;
        for (int d = 0; d < DF; ++d)
            s += (double)W[k * NCOL + hh * DF + d] * (double)attn[hh * DF + d];
        Wlr[k * 8 + j] = s;
    }
}

// ---------------- K1: h = x @ W (fp32) ----------------
// 32-row tile, xs staged ONCE (single barrier), W streamed from L1/L2.
// N_SRC = 3125 * 32 exactly -> no bounds checks.
__global__ __launch_bounds__(256) void k_gemm(const float* __restrict__ x,
                                              const float* __restrict__ W,
                                              float* __restrict__ h) {
    __shared__ float xs[32][IN_F];  // 32 KB
    const int tid = threadIdx.x;
    const int row0 = blockIdx.x * 32;

    // stage x tile: 32 rows x 64 float4 = 2048 float4, 8 per thread (coalesced)
#pragma unroll
    for (int t = 0; t < 8; ++t) {
        int i = t * 256 + tid;
        int r = i >> 6;     // 0..31
        int q = i & 63;     // float4 index within row
        ((float4*)&xs[r][0])[q] =
            *((const float4*)(x + (size_t)(row0 + r) * IN_F + q * 4));
    }
    __syncthreads();

    const int c0 = (tid & 31) * 4;   // 4 consecutive cols
    const int r0 = (tid >> 5) * 4;   // 4 consecutive rows

    float acc[4][4];
#pragma unroll
    for (int j = 0; j < 4; ++j)
#pragma unroll
        for (int m = 0; m < 4; ++m) acc[j][m] = 0.f;

#pragma unroll 4
    for (int k = 0; k < IN_F; k += 4) {
        const float* wp = W + (size_t)k * NCOL + c0;
        float4 w0 = *((const float4*)(wp));
        float4 w1 = *((const float4*)(wp + NCOL));
        float4 w2 = *((const float4*)(wp + 2 * NCOL));
        float4 w3 = *((const float4*)(wp + 3 * NCOL));
#pragma unroll
        for (int j = 0; j < 4; ++j) {
            float4 xv = *((const float4*)&xs[r0 + j][k]);
            acc[j][0] += xv.x * w0.x + xv.y * w1.x + xv.z * w2.x + xv.w * w3.x;
            acc[j][1] += xv.x * w0.y + xv.y * w1.y + xv.z * w2.y + xv.w * w3.y;
            acc[j][2] += xv.x * w0.z + xv.y * w1.z + xv.z * w2.z + xv.w * w3.z;
            acc[j][3] += xv.x * w0.w + xv.y * w1.w + xv.z * w2.w + xv.w * w3.w;
        }
    }

#pragma unroll
    for (int j = 0; j < 4; ++j) {
        int row = row0 + r0 + j;
        *((float4*)(h + (size_t)row * NCOL + c0)) =
            make_float4(acc[j][0], acc[j][1], acc[j][2], acc[j][3]);
    }
}

// ---------------- K2: el / er_src via fp64 dot(x_row, Wlr) ----------------
__global__ __launch_bounds__(256) void k_scores(const float* __restrict__ x,
                                                const double* __restrict__ Wlr,
                                                double* __restrict__ el,
                                                double* __restrict__ er_src) {
    const int lane = threadIdx.x & 63;
    const int wid = (blockIdx.x * 256 + threadIdx.x) >> 6;
    const int nwaves = gridDim.x * 4;

    double wreg[4][8];
#pragma unroll
    for (int i = 0; i < 4; ++i)
#pragma unroll
        for (int j = 0; j < 8; ++j)
            wreg[i][j] = Wlr[(lane * 4 + i) * 8 + j];

    for (int row = wid; row < N_SRC; row += nwaves) {
        float4 xv = *((const float4*)(x + (size_t)row * IN_F + lane * 4));
        double acc[8];
#pragma unroll
        for (int j = 0; j < 8; ++j) acc[j] = 0.0;
        const double xd[4] = {(double)xv.x, (double)xv.y, (double)xv.z, (double)xv.w};
#pragma unroll
        for (int i = 0; i < 4; ++i)
#pragma unroll
            for (int j = 0; j < 8; ++j)
                acc[j] += xd[i] * wreg[i][j];
#pragma unroll
        for (int j = 0; j < 8; ++j) {
#pragma unroll
            for (int m = 32; m >= 1; m >>= 1)
                acc[j] += __shfl_xor(acc[j], m);
        }
        if (lane == 0) {
#pragma unroll
            for (int hh = 0; hh < 4; ++hh) {
                el[(size_t)row * NH + hh] = acc[hh];
                er_src[(size_t)row * NH + hh] = acc[4 + hh];
            }
        }
    }
}

// ---------------- K3: gather er for dst nodes ----------------
__global__ __launch_bounds__(256) void k_gather(const int* __restrict__ dst_to_src,
                                                const double* __restrict__ er_src,
                                                double* __restrict__ er_dst) {
    int gid = blockIdx.x * 256 + threadIdx.x;
    if (gid >= N_DST * NH) return;
    int nd = gid >> 2, hh = gid & 3;
    er_dst[gid] = er_src[(size_t)dst_to_src[nd] * NH + hh];
}

// ---------------- CSR build ----------------
__global__ __launch_bounds__(256) void k_hist(const int* __restrict__ dst_idx,
                                              int* __restrict__ cnt) {
    int gid = blockIdx.x * 256 + threadIdx.x;
    if (gid >= NE) return;
    atomicAdd(cnt + dst_idx[gid], 1);
}

__global__ __launch_bounds__(1024) void k_scan(const int* __restrict__ cnt,
                                               int* __restrict__ offsets) {
    __shared__ int wsum[16];
    __shared__ int carry;
    int tid = threadIdx.x, lane = tid & 63, w = tid >> 6;
    if (tid == 0) carry = 0;
    __syncthreads();
    for (int base = 0; base < N_DST; base += 1024) {
        int i = base + tid;
        int v = (i < N_DST) ? cnt[i] : 0;
        int s = v;
#pragma unroll
        for (int off = 1; off < 64; off <<= 1) {
            int t = __shfl_up(s, off);
            if (lane >= off) s += t;
        }
        if (lane == 63) wsum[w] = s;
        __syncthreads();
        int wprefix = 0;
        for (int k = 0; k < w; ++k) wprefix += wsum[k];
        int incl = s + wprefix + carry;
        if (i < N_DST) offsets[i + 1] = incl;
        __syncthreads();
        if (tid == 1023) carry = incl;
        __syncthreads();
    }
    if (tid == 0) offsets[0] = 0;
}

__global__ __launch_bounds__(256) void k_fill(const int* __restrict__ src_idx,
                                              const int* __restrict__ dst_idx,
                                              const int* __restrict__ offsets,
                                              int* __restrict__ cursor,
                                              int* __restrict__ edge_src) {
    int gid = blockIdx.x * 256 + threadIdx.x;
    if (gid >= NE) return;
    int d = dst_idx[gid];
    int pos = offsets[d] + atomicAdd(cursor + d, 1);
    edge_src[pos] = src_idx[gid];
}

// ---------------- K5: fused segment-sum + normalize + weighted gather ----------------
// one block (128 threads) per dst node
__global__ __launch_bounds__(128) void k_fused(const int* __restrict__ offsets,
                                               const int* __restrict__ edge_src,
                                               const double* __restrict__ el,
                                               const double* __restrict__ er_dst,
                                               const float* __restrict__ h,
                                               float* __restrict__ out) {
    const int d = blockIdx.x;
    const int tid = threadIdx.x;
    const int beg = offsets[d];
    const int deg = offsets[d + 1] - beg;

    __shared__ double e_lds[MAXE][NH];  // 8 KB
    __shared__ int s_lds[MAXE];         // 1 KB
    __shared__ double red[128][NH];     // 4 KB
    __shared__ double S_sh[NH];
    __shared__ double facc[4][32][4];   // 4 KB

    double er4[NH];
#pragma unroll
    for (int hh = 0; hh < NH; ++hh) er4[hh] = er_dst[(size_t)d * NH + hh];

    // phase 1: per-edge scores, cache in LDS, block-sum S
    double sum4[NH] = {0.0, 0.0, 0.0, 0.0};
    for (int j = tid; j < deg; j += 128) {
        int s = edge_src[beg + j];
        if (j < MAXE) s_lds[j] = s;
        const double* elp = el + (size_t)s * NH;
#pragma unroll
        for (int hh = 0; hh < NH; ++hh) {
            double e = elp[hh] + er4[hh];
            e = (e >= 0.0) ? e : 0.2 * e;
            if (j < MAXE) e_lds[j][hh] = e;
            sum4[hh] += e;
        }
    }
#pragma unroll
    for (int hh = 0; hh < NH; ++hh) red[tid][hh] = sum4[hh];
    __syncthreads();
    for (int off = 64; off >= 1; off >>= 1) {
        if (tid < off) {
#pragma unroll
            for (int hh = 0; hh < NH; ++hh) red[tid][hh] += red[tid + off][hh];
        }
        __syncthreads();
    }
    if (tid < NH) S_sh[tid] = red[0][tid];
    __syncthreads();

    // phase 2: 4 edges in flight; thread = (edge sublane js, col quad cq)
    const int js = tid >> 5;
    const int cq = tid & 31;
    const int hd = cq >> 3;  // head for cols cq*4..cq*4+3
    const double Sinv = (deg > 0) ? 1.0 / S_sh[hd] : 0.0;

    double acc[4] = {0.0, 0.0, 0.0, 0.0};
    for (int j = js; j < deg; j += 4) {
        int s;
        double e;
        if (j < MAXE) {
            s = s_lds[j];
            e = e_lds[j][hd];
        } else {
            s = edge_src[beg + j];
            e = el[(size_t)s * NH + hd] + er4[hd];
            e = (e >= 0.0) ? e : 0.2 * e;
        }
        double att = e * Sinv;
        float4 hv = *((const float4*)(h + (size_t)s * NCOL + cq * 4));
        acc[0] += att * (double)hv.x;
        acc[1] += att * (double)hv.y;
        acc[2] += att * (double)hv.z;
        acc[3] += att * (double)hv.w;
    }
#pragma unroll
    for (int m = 0; m < 4; ++m) facc[js][cq][m] = acc[m];
    __syncthreads();
    if (tid < 32) {
        float4 o;
        o.x = (float)(facc[0][tid][0] + facc[1][tid][0] + facc[2][tid][0] + facc[3][tid][0]);
        o.y = (float)(facc[0][tid][1] + facc[1][tid][1] + facc[2][tid][1] + facc[3][tid][1]);
        o.z = (float)(facc[0][tid][2] + facc[1][tid][2] + facc[2][tid][2] + facc[3][tid][2]);
        o.w = (float)(facc[0][tid][3] + facc[1][tid][3] + facc[2][tid][3] + facc[3][tid][3]);
        *((float4*)(out + (size_t)d * NCOL + tid * 4)) = o;
    }
}

extern "C" void kernel_launch(void* const* d_in, const int* in_sizes, int n_in,
                              void* d_out, int out_size, void* d_ws, size_t ws_size,
                              hipStream_t stream) {
    const float* x      = (const float*)d_in[0];
    const float* W      = (const float*)d_in[1];
    const float* attn_l = (const float*)d_in[2];
    const float* attn_r = (const float*)d_in[3];
    const int* src_idx  = (const int*)d_in[4];
    const int* dst_idx  = (const int*)d_in[5];
    const int* dst_to_src = (const int*)d_in[6];
    float* out = (float*)d_out;

    char* p = (char*)d_ws;
    double* Wlr    = (double*)p;  p += (size_t)IN_F * 8 * sizeof(double);
    double* el     = (double*)p;  p += (size_t)N_SRC * NH * sizeof(double);
    double* er_src = (double*)p;  p += (size_t)N_SRC * NH * sizeof(double);
    double* er_dst = (double*)p;  p += (size_t)N_DST * NH * sizeof(double);
    float*  h      = (float*)p;   p += (size_t)N_SRC * NCOL * sizeof(float);
    int*    cnt      = (int*)p;   p += (size_t)N_DST * sizeof(int);
    int*    offsets  = (int*)p;   p += (size_t)(N_DST + 1) * sizeof(int);
    int*    cursor   = (int*)p;   p += (size_t)N_DST * sizeof(int);
    int*    edge_src = (int*)p;   p += (size_t)NE * sizeof(int);

    hipMemsetAsync(cnt, 0, (size_t)N_DST * sizeof(int), stream);
    hipMemsetAsync(cursor, 0, (size_t)N_DST * sizeof(int), stream);

    k_prep<<<1, IN_F, 0, stream>>>(W, attn_l, attn_r, Wlr);
    k_gemm<<<N_SRC / 32, 256, 0, stream>>>(x, W, h);
    k_scores<<<512, 256, 0, stream>>>(x, Wlr, el, er_src);
    k_gather<<<(N_DST * NH + 255) / 256, 256, 0, stream>>>(dst_to_src, er_src, er_dst);
    k_hist<<<(NE + 255) / 256, 256, 0, stream>>>(dst_idx, cnt);
    k_scan<<<1, 1024, 0, stream>>>(cnt, offsets);
    k_fill<<<(NE + 255) / 256, 256, 0, stream>>>(src_idx, dst_idx, offsets, cursor, edge_src);
    k_fused<<<N_DST, 128, 0, stream>>>(offsets, edge_src, el, er_dst, h, out);
}

// Round 7
// 403.132 us; speedup vs baseline: 1.6502x; 1.0183x over previous
//
#include <hip/hip_runtime.h>

#define N_SRC 100000
#define N_DST 20000
#define NE 640000
#define IN_F 256
#define NH 4
#define DF 32
#define NCOL 128  /* NH*DF */
#define TR 64     /* gemm tile rows */
#define LPAD 132  /* padded LDS row (floats) */

// ---------------- K1: h = x @ W (fp32) ----------------
// 64-row tile, K split into two 128-halves staged in LDS; 8 rows x 4 cols
// per thread. Per-output k-accumulation order identical to prior rounds
// (quads k,k+1,k+2,k+3 in ascending k) -> h bit-identical.
__global__ __launch_bounds__(256) void k_gemm(const float* __restrict__ x,
                                              const float* __restrict__ W,
                                              float* __restrict__ h) {
    __shared__ float xs[TR][LPAD];  // 33 KB
    const int tid = threadIdx.x;
    const int row0 = blockIdx.x * TR;
    const int cg = tid & 31;   // col group -> cols cg*4..+3
    const int rg = tid >> 5;   // row group -> rows rg*8..+7
    const int c0 = cg * 4;
    const int r0 = rg * 8;

    float acc[8][4];
#pragma unroll
    for (int j = 0; j < 8; ++j)
#pragma unroll
        for (int m = 0; m < 4; ++m) acc[j][m] = 0.f;

    for (int half = 0; half < 2; ++half) {
        const int kbase = half * 128;
        if (half) __syncthreads();  // protect xs reuse
        // stage 64 rows x 128 k: 2048 float4, 8 per thread, coalesced
#pragma unroll
        for (int t = 0; t < 8; ++t) {
            int i = t * 256 + tid;
            int r = i >> 5;     // 0..63
            int q = i & 31;     // float4 within the 128-k half
            int row = row0 + r;
            float4 v = make_float4(0.f, 0.f, 0.f, 0.f);
            if (row < N_SRC)
                v = *((const float4*)(x + (size_t)row * IN_F + kbase + q * 4));
            *((float4*)&xs[r][q * 4]) = v;
        }
        __syncthreads();

#pragma unroll 2
        for (int kq = 0; kq < 128; kq += 4) {
            const float* wp = W + (size_t)(kbase + kq) * NCOL + c0;
            float4 w0 = *((const float4*)(wp));
            float4 w1 = *((const float4*)(wp + NCOL));
            float4 w2 = *((const float4*)(wp + 2 * NCOL));
            float4 w3 = *((const float4*)(wp + 3 * NCOL));
#pragma unroll
            for (int j = 0; j < 8; ++j) {
                float4 xv = *((const float4*)&xs[r0 + j][kq]);
                acc[j][0] += xv.x * w0.x + xv.y * w1.x + xv.z * w2.x + xv.w * w3.x;
                acc[j][1] += xv.x * w0.y + xv.y * w1.y + xv.z * w2.y + xv.w * w3.y;
                acc[j][2] += xv.x * w0.z + xv.y * w1.z + xv.z * w2.z + xv.w * w3.z;
                acc[j][3] += xv.x * w0.w + xv.y * w1.w + xv.z * w2.w + xv.w * w3.w;
            }
        }
    }

#pragma unroll
    for (int j = 0; j < 8; ++j) {
        int row = row0 + r0 + j;
        if (row < N_SRC)
            *((float4*)(h + (size_t)row * NCOL + c0)) =
                make_float4(acc[j][0], acc[j][1], acc[j][2], acc[j][3]);
    }
}

// ---------------- K2: el / er_src (fp64) + edge histogram ----------------
// Each block folds attn into per-lane Wlr slices from W directly (no k_prep
// kernel, no Wlr buffer). Tail: grid-stride histogram of dst_idx into cnt.
__global__ __launch_bounds__(256) void k_scores(const float* __restrict__ x,
                                                const float* __restrict__ W,
                                                const float* __restrict__ attn_l,
                                                const float* __restrict__ attn_r,
                                                const int* __restrict__ dst_idx,
                                                double* __restrict__ el,
                                                double* __restrict__ er_src,
                                                int* __restrict__ cnt) {
    const int lane = threadIdx.x & 63;
    const int wid = (blockIdx.x * 256 + threadIdx.x) >> 6;
    const int nwaves = gridDim.x * 4;

    // per-lane Wlr slice computed locally (fp64)
    double wreg[4][8];
#pragma unroll
    for (int i = 0; i < 4; ++i) {
        const float* wrow = W + (size_t)(lane * 4 + i) * NCOL;
#pragma unroll
        for (int j = 0; j < 8; ++j) {
            const float* attn = (j < 4) ? attn_l : attn_r;
            int hh = j & 3;
            double s = 0.0;
            for (int d = 0; d < DF; ++d)
                s += (double)wrow[hh * DF + d] * (double)attn[hh * DF + d];
            wreg[i][j] = s;
        }
    }

    for (int row = wid; row < N_SRC; row += nwaves) {
        float4 xv = *((const float4*)(x + (size_t)row * IN_F + lane * 4));
        double acc[8];
#pragma unroll
        for (int j = 0; j < 8; ++j) acc[j] = 0.0;
        const double xd[4] = {(double)xv.x, (double)xv.y, (double)xv.z, (double)xv.w};
#pragma unroll
        for (int i = 0; i < 4; ++i)
#pragma unroll
            for (int j = 0; j < 8; ++j)
                acc[j] += xd[i] * wreg[i][j];
#pragma unroll
        for (int j = 0; j < 8; ++j) {
#pragma unroll
            for (int m = 32; m >= 1; m >>= 1)
                acc[j] += __shfl_xor(acc[j], m);
        }
        if (lane == 0) {
#pragma unroll
            for (int hh = 0; hh < 4; ++hh) {
                el[(size_t)row * NH + hh] = acc[hh];
                er_src[(size_t)row * NH + hh] = acc[4 + hh];
            }
        }
    }

    // fused histogram (cnt was zeroed by the preceding memset)
    for (int e = blockIdx.x * 256 + threadIdx.x; e < NE; e += gridDim.x * 256)
        atomicAdd(cnt + dst_idx[e], 1);
}

// ---------------- k_scan: exclusive scan of cnt -> offsets; zero cursor ----
__global__ __launch_bounds__(1024) void k_scan(const int* __restrict__ cnt,
                                               int* __restrict__ offsets,
                                               int* __restrict__ cursor) {
    __shared__ int wsum[16];
    __shared__ int carry;
    int tid = threadIdx.x, lane = tid & 63, w = tid >> 6;
    if (tid == 0) carry = 0;
    __syncthreads();
    for (int base = 0; base < N_DST; base += 1024) {
        int i = base + tid;
        int v = (i < N_DST) ? cnt[i] : 0;
        int s = v;
#pragma unroll
        for (int off = 1; off < 64; off <<= 1) {
            int t = __shfl_up(s, off);
            if (lane >= off) s += t;
        }
        if (lane == 63) wsum[w] = s;
        __syncthreads();
        int wprefix = 0;
        for (int k = 0; k < w; ++k) wprefix += wsum[k];
        int incl = s + wprefix + carry;
        if (i < N_DST) {
            offsets[i + 1] = incl;
            cursor[i] = 0;
        }
        __syncthreads();
        if (tid == 1023) carry = incl;
        __syncthreads();
    }
    if (tid == 0) offsets[0] = 0;
}

__global__ __launch_bounds__(256) void k_fill(const int* __restrict__ src_idx,
                                              const int* __restrict__ dst_idx,
                                              const int* __restrict__ offsets,
                                              int* __restrict__ cursor,
                                              int* __restrict__ edge_src) {
    int gid = blockIdx.x * 256 + threadIdx.x;
    if (gid >= NE) return;
    int d = dst_idx[gid];
    int pos = offsets[d] + atomicAdd(cursor + d, 1);
    edge_src[pos] = src_idx[gid];
}

// ---------------- K5: fused S + normalize + weighted gather ----------------
// one WAVE per dst node (4 dst per 256-thread block); no barriers, no LDS.
__global__ __launch_bounds__(256) void k_fused(const int* __restrict__ offsets,
                                               const int* __restrict__ edge_src,
                                               const double* __restrict__ el,
                                               const double* __restrict__ er_src,
                                               const int* __restrict__ dst_to_src,
                                               const float* __restrict__ h,
                                               float* __restrict__ out) {
    const int lane = threadIdx.x & 63;
    const int d = blockIdx.x * 4 + (threadIdx.x >> 6);
    if (d >= N_DST) return;
    const int beg = offsets[d];
    const int deg = offsets[d + 1] - beg;

    const int srcd = dst_to_src[d];
    double er4[NH];
#pragma unroll
    for (int hh = 0; hh < NH; ++hh) er4[hh] = er_src[(size_t)srcd * NH + hh];

    // phase 1: S[h] via per-lane partial + wave butterfly (fp64)
    double sum4[NH] = {0.0, 0.0, 0.0, 0.0};
    for (int j = lane; j < deg; j += 64) {
        int s = edge_src[beg + j];
        const double* elp = el + (size_t)s * NH;
#pragma unroll
        for (int hh = 0; hh < NH; ++hh) {
            double e = elp[hh] + er4[hh];
            e = (e >= 0.0) ? e : 0.2 * e;
            sum4[hh] += e;
        }
    }
#pragma unroll
    for (int hh = 0; hh < NH; ++hh) {
#pragma unroll
        for (int m = 32; m >= 1; m >>= 1)
            sum4[hh] += __shfl_xor(sum4[hh], m);
    }

    // phase 2: 2 edges in flight; lane = (js, col quad cq)
    const int js = lane >> 5;
    const int cq = lane & 31;
    const int hd = cq >> 3;
    const double Sinv = (deg > 0) ? 1.0 / sum4[hd] : 0.0;

    double acc[4] = {0.0, 0.0, 0.0, 0.0};
    for (int j = js; j < deg; j += 2) {
        int s = edge_src[beg + j];
        double e = el[(size_t)s * NH + hd] + er4[hd];
        e = (e >= 0.0) ? e : 0.2 * e;
        double att = e * Sinv;
        float4 hv = *((const float4*)(h + (size_t)s * NCOL + cq * 4));
        acc[0] += att * (double)hv.x;
        acc[1] += att * (double)hv.y;
        acc[2] += att * (double)hv.z;
        acc[3] += att * (double)hv.w;
    }
    // combine the two js halves
#pragma unroll
    for (int m = 0; m < 4; ++m) acc[m] += __shfl_xor(acc[m], 32);

    if (lane < 32) {
        *((float4*)(out + (size_t)d * NCOL + lane * 4)) =
            make_float4((float)acc[0], (float)acc[1], (float)acc[2], (float)acc[3]);
    }
}

extern "C" void kernel_launch(void* const* d_in, const int* in_sizes, int n_in,
                              void* d_out, int out_size, void* d_ws, size_t ws_size,
                              hipStream_t stream) {
    const float* x      = (const float*)d_in[0];
    const float* W      = (const float*)d_in[1];
    const float* attn_l = (const float*)d_in[2];
    const float* attn_r = (const float*)d_in[3];
    const int* src_idx  = (const int*)d_in[4];
    const int* dst_idx  = (const int*)d_in[5];
    const int* dst_to_src = (const int*)d_in[6];
    float* out = (float*)d_out;

    char* p = (char*)d_ws;
    double* el     = (double*)p;  p += (size_t)N_SRC * NH * sizeof(double);   // 3.2 MB
    double* er_src = (double*)p;  p += (size_t)N_SRC * NH * sizeof(double);   // 3.2 MB
    float*  h      = (float*)p;   p += (size_t)N_SRC * NCOL * sizeof(float);  // 51.2 MB
    int*    cnt      = (int*)p;   p += (size_t)N_DST * sizeof(int);
    int*    offsets  = (int*)p;   p += (size_t)(N_DST + 1) * sizeof(int);
    int*    cursor   = (int*)p;   p += (size_t)N_DST * sizeof(int);
    int*    edge_src = (int*)p;   p += (size_t)NE * sizeof(int);

    hipMemsetAsync(cnt, 0, (size_t)N_DST * sizeof(int), stream);

    k_gemm<<<(N_SRC + TR - 1) / TR, 256, 0, stream>>>(x, W, h);
    k_scores<<<512, 256, 0, stream>>>(x, W, attn_l, attn_r, dst_idx, el, er_src, cnt);
    k_scan<<<1, 1024, 0, stream>>>(cnt, offsets, cursor);
    k_fill<<<(NE + 255) / 256, 256, 0, stream>>>(src_idx, dst_idx, offsets, cursor, edge_src);
    k_fused<<<N_DST / 4, 256, 0, stream>>>(offsets, edge_src, el, er_src, dst_to_src, h, out);
}

// Round 8
// 389.028 us; speedup vs baseline: 1.7100x; 1.0363x over previous
//
#include <hip/hip_runtime.h>

#define N_SRC 100000
#define N_DST 20000
#define NE 640000
#define IN_F 256
#define NH 4
#define DF 32
#define NCOL 128  /* NH*DF */

// ---------------- K1: h = x @ W (fp32) ----------------
// 32-row tile; K staged in two 128-halves -> xs = 16 KB exactly -> 8 blocks/CU
// (32 waves/CU). 4 rows x 4 cols per thread keeps VGPR at 64 (8 waves/SIMD
// boundary, m69). Per-output k-order identical to prior rounds -> h bit-identical.
// N_SRC = 3125 * 32 exactly -> no bounds checks.
__global__ __launch_bounds__(256) void k_gemm(const float* __restrict__ x,
                                              const float* __restrict__ W,
                                              float* __restrict__ h) {
    __shared__ float xs[32][128];  // 16 KB exact
    const int tid = threadIdx.x;
    const int row0 = blockIdx.x * 32;
    const int c0 = (tid & 31) * 4;   // 4 consecutive cols
    const int r0 = (tid >> 5) * 4;   // 4 consecutive rows

    float acc[4][4];
#pragma unroll
    for (int j = 0; j < 4; ++j)
#pragma unroll
        for (int m = 0; m < 4; ++m) acc[j][m] = 0.f;

    for (int half = 0; half < 2; ++half) {
        const int kbase = half * 128;
        if (half) __syncthreads();  // xs readers done before overwrite
        // stage 32 rows x 128 k: 1024 float4, 4 per thread, coalesced
#pragma unroll
        for (int t = 0; t < 4; ++t) {
            int i = t * 256 + tid;
            int r = i >> 5;     // 0..31
            int q = i & 31;     // float4 index within 128-k half
            *((float4*)&xs[r][q * 4]) =
                *((const float4*)(x + (size_t)(row0 + r) * IN_F + kbase + q * 4));
        }
        __syncthreads();

#pragma unroll 4
        for (int kq = 0; kq < 128; kq += 4) {
            const float* wp = W + (size_t)(kbase + kq) * NCOL + c0;
            float4 w0 = *((const float4*)(wp));
            float4 w1 = *((const float4*)(wp + NCOL));
            float4 w2 = *((const float4*)(wp + 2 * NCOL));
            float4 w3 = *((const float4*)(wp + 3 * NCOL));
#pragma unroll
            for (int j = 0; j < 4; ++j) {
                float4 xv = *((const float4*)&xs[r0 + j][kq]);
                acc[j][0] += xv.x * w0.x + xv.y * w1.x + xv.z * w2.x + xv.w * w3.x;
                acc[j][1] += xv.x * w0.y + xv.y * w1.y + xv.z * w2.y + xv.w * w3.y;
                acc[j][2] += xv.x * w0.z + xv.y * w1.z + xv.z * w2.z + xv.w * w3.z;
                acc[j][3] += xv.x * w0.w + xv.y * w1.w + xv.z * w2.w + xv.w * w3.w;
            }
        }
    }

#pragma unroll
    for (int j = 0; j < 4; ++j) {
        int row = row0 + r0 + j;
        *((float4*)(h + (size_t)row * NCOL + c0)) =
            make_float4(acc[j][0], acc[j][1], acc[j][2], acc[j][3]);
    }
}

// ---------------- K2: el / er_src (fp64) + edge histogram ----------------
__global__ __launch_bounds__(256) void k_scores(const float* __restrict__ x,
                                                const float* __restrict__ W,
                                                const float* __restrict__ attn_l,
                                                const float* __restrict__ attn_r,
                                                const int* __restrict__ dst_idx,
                                                double* __restrict__ el,
                                                double* __restrict__ er_src,
                                                int* __restrict__ cnt) {
    const int lane = threadIdx.x & 63;
    const int wid = (blockIdx.x * 256 + threadIdx.x) >> 6;
    const int nwaves = gridDim.x * 4;

    // per-lane Wlr slice computed locally (fp64)
    double wreg[4][8];
#pragma unroll
    for (int i = 0; i < 4; ++i) {
        const float* wrow = W + (size_t)(lane * 4 + i) * NCOL;
#pragma unroll
        for (int j = 0; j < 8; ++j) {
            const float* attn = (j < 4) ? attn_l : attn_r;
            int hh = j & 3;
            double s = 0.0;
            for (int d = 0; d < DF; ++d)
                s += (double)wrow[hh * DF + d] * (double)attn[hh * DF + d];
            wreg[i][j] = s;
        }
    }

    for (int row = wid; row < N_SRC; row += nwaves) {
        float4 xv = *((const float4*)(x + (size_t)row * IN_F + lane * 4));
        double acc[8];
#pragma unroll
        for (int j = 0; j < 8; ++j) acc[j] = 0.0;
        const double xd[4] = {(double)xv.x, (double)xv.y, (double)xv.z, (double)xv.w};
#pragma unroll
        for (int i = 0; i < 4; ++i)
#pragma unroll
            for (int j = 0; j < 8; ++j)
                acc[j] += xd[i] * wreg[i][j];
#pragma unroll
        for (int j = 0; j < 8; ++j) {
#pragma unroll
            for (int m = 32; m >= 1; m >>= 1)
                acc[j] += __shfl_xor(acc[j], m);
        }
        if (lane == 0) {
#pragma unroll
            for (int hh = 0; hh < 4; ++hh) {
                el[(size_t)row * NH + hh] = acc[hh];
                er_src[(size_t)row * NH + hh] = acc[4 + hh];
            }
        }
    }

    // fused histogram (cnt zeroed by the preceding memset)
    for (int e = blockIdx.x * 256 + threadIdx.x; e < NE; e += gridDim.x * 256)
        atomicAdd(cnt + dst_idx[e], 1);
}

// ---------------- k_scan: exclusive scan of cnt -> offsets; zero cursor ----
__global__ __launch_bounds__(1024) void k_scan(const int* __restrict__ cnt,
                                               int* __restrict__ offsets,
                                               int* __restrict__ cursor) {
    __shared__ int wsum[16];
    __shared__ int carry;
    int tid = threadIdx.x, lane = tid & 63, w = tid >> 6;
    if (tid == 0) carry = 0;
    __syncthreads();
    for (int base = 0; base < N_DST; base += 1024) {
        int i = base + tid;
        int v = (i < N_DST) ? cnt[i] : 0;
        int s = v;
#pragma unroll
        for (int off = 1; off < 64; off <<= 1) {
            int t = __shfl_up(s, off);
            if (lane >= off) s += t;
        }
        if (lane == 63) wsum[w] = s;
        __syncthreads();
        int wprefix = 0;
        for (int k = 0; k < w; ++k) wprefix += wsum[k];
        int incl = s + wprefix + carry;
        if (i < N_DST) {
            offsets[i + 1] = incl;
            cursor[i] = 0;
        }
        __syncthreads();
        if (tid == 1023) carry = incl;
        __syncthreads();
    }
    if (tid == 0) offsets[0] = 0;
}

__global__ __launch_bounds__(256) void k_fill(const int* __restrict__ src_idx,
                                              const int* __restrict__ dst_idx,
                                              const int* __restrict__ offsets,
                                              int* __restrict__ cursor,
                                              int* __restrict__ edge_src) {
    int gid = blockIdx.x * 256 + threadIdx.x;
    if (gid >= NE) return;
    int d = dst_idx[gid];
    int pos = offsets[d] + atomicAdd(cursor + d, 1);
    edge_src[pos] = src_idx[gid];
}

// ---------------- K5: fused S + normalize + weighted gather ----------------
// one WAVE per dst node (4 dst per 256-thread block); no barriers, no LDS.
__global__ __launch_bounds__(256) void k_fused(const int* __restrict__ offsets,
                                               const int* __restrict__ edge_src,
                                               const double* __restrict__ el,
                                               const double* __restrict__ er_src,
                                               const int* __restrict__ dst_to_src,
                                               const float* __restrict__ h,
                                               float* __restrict__ out) {
    const int lane = threadIdx.x & 63;
    const int d = blockIdx.x * 4 + (threadIdx.x >> 6);
    if (d >= N_DST) return;
    const int beg = offsets[d];
    const int deg = offsets[d + 1] - beg;

    const int srcd = dst_to_src[d];
    double er4[NH];
#pragma unroll
    for (int hh = 0; hh < NH; ++hh) er4[hh] = er_src[(size_t)srcd * NH + hh];

    // phase 1: S[h] via per-lane partial + wave butterfly (fp64)
    double sum4[NH] = {0.0, 0.0, 0.0, 0.0};
    for (int j = lane; j < deg; j += 64) {
        int s = edge_src[beg + j];
        const double* elp = el + (size_t)s * NH;
#pragma unroll
        for (int hh = 0; hh < NH; ++hh) {
            double e = elp[hh] + er4[hh];
            e = (e >= 0.0) ? e : 0.2 * e;
            sum4[hh] += e;
        }
    }
#pragma unroll
    for (int hh = 0; hh < NH; ++hh) {
#pragma unroll
        for (int m = 32; m >= 1; m >>= 1)
            sum4[hh] += __shfl_xor(sum4[hh], m);
    }

    // phase 2: 2 edges in flight; lane = (js, col quad cq)
    const int js = lane >> 5;
    const int cq = lane & 31;
    const int hd = cq >> 3;
    const double Sinv = (deg > 0) ? 1.0 / sum4[hd] : 0.0;

    double acc[4] = {0.0, 0.0, 0.0, 0.0};
    for (int j = js; j < deg; j += 2) {
        int s = edge_src[beg + j];
        double e = el[(size_t)s * NH + hd] + er4[hd];
        e = (e >= 0.0) ? e : 0.2 * e;
        double att = e * Sinv;
        float4 hv = *((const float4*)(h + (size_t)s * NCOL + cq * 4));
        acc[0] += att * (double)hv.x;
        acc[1] += att * (double)hv.y;
        acc[2] += att * (double)hv.z;
        acc[3] += att * (double)hv.w;
    }
#pragma unroll
    for (int m = 0; m < 4; ++m) acc[m] += __shfl_xor(acc[m], 32);

    if (lane < 32) {
        *((float4*)(out + (size_t)d * NCOL + lane * 4)) =
            make_float4((float)acc[0], (float)acc[1], (float)acc[2], (float)acc[3]);
    }
}

extern "C" void kernel_launch(void* const* d_in, const int* in_sizes, int n_in,
                              void* d_out, int out_size, void* d_ws, size_t ws_size,
                              hipStream_t stream) {
    const float* x      = (const float*)d_in[0];
    const float* W      = (const float*)d_in[1];
    const float* attn_l = (const float*)d_in[2];
    const float* attn_r = (const float*)d_in[3];
    const int* src_idx  = (const int*)d_in[4];
    const int* dst_idx  = (const int*)d_in[5];
    const int* dst_to_src = (const int*)d_in[6];
    float* out = (float*)d_out;

    char* p = (char*)d_ws;
    double* el     = (double*)p;  p += (size_t)N_SRC * NH * sizeof(double);   // 3.2 MB
    double* er_src = (double*)p;  p += (size_t)N_SRC * NH * sizeof(double);   // 3.2 MB
    float*  h      = (float*)p;   p += (size_t)N_SRC * NCOL * sizeof(float);  // 51.2 MB
    int*    cnt      = (int*)p;   p += (size_t)N_DST * sizeof(int);
    int*    offsets  = (int*)p;   p += (size_t)(N_DST + 1) * sizeof(int);
    int*    cursor   = (int*)p;   p += (size_t)N_DST * sizeof(int);
    int*    edge_src = (int*)p;   p += (size_t)NE * sizeof(int);

    hipMemsetAsync(cnt, 0, (size_t)N_DST * sizeof(int), stream);

    k_gemm<<<N_SRC / 32, 256, 0, stream>>>(x, W, h);
    k_scores<<<1024, 256, 0, stream>>>(x, W, attn_l, attn_r, dst_idx, el, er_src, cnt);
    k_scan<<<1, 1024, 0, stream>>>(cnt, offsets, cursor);
    k_fill<<<(NE + 255) / 256, 256, 0, stream>>>(src_idx, dst_idx, offsets, cursor, edge_src);
    k_fused<<<N_DST / 4, 256, 0, stream>>>(offsets, edge_src, el, er_src, dst_to_src, h, out);
}

// Round 10
// 311.811 us; speedup vs baseline: 2.1335x; 1.2476x over previous
//
#include <hip/hip_runtime.h>

#define N_SRC 100000
#define N_DST 20000
#define NE 640000
#define IN_F 256
#define NH 4
#define DF 32
#define NCOL 128  /* NH*DF */

// ---------------- K0: fold attn vectors into W (fp64), k-per-thread ----------
// Wlr_t[j][k] = sum_d W[k][(j&3)*32+d] * attn_{l:j<4, r:j>=4}[(j&3)*32+d]
__global__ void k_prep(const float* __restrict__ W,
                       const float* __restrict__ attn_l,
                       const float* __restrict__ attn_r,
                       double* __restrict__ Wlr_t) {
    int k = threadIdx.x;  // 256 threads
    for (int j = 0; j < 8; ++j) {
        const float* attn = (j < 4) ? attn_l : attn_r;
        int hh = j & 3;
        double s = 0.0;
        for (int d = 0; d < DF; ++d)
            s += (double)W[k * NCOL + hh * DF + d] * (double)attn[hh * DF + d];
        Wlr_t[(size_t)j * IN_F + k] = s;
    }
}

// ---------------- K1: h = x @ W (fp32) ----------------
// round-8's proven pure GEMM: 32-row tile, two 128-k halves, xs = 16 KB,
// VGPR ~64, h bit-identical k-order. N_SRC = 3125*32 -> no bounds checks.
__global__ __launch_bounds__(256) void k_gemm(const float* __restrict__ x,
                                              const float* __restrict__ W,
                                              float* __restrict__ h) {
    __shared__ float xs[32][128];  // 16 KB
    const int tid = threadIdx.x;
    const int row0 = blockIdx.x * 32;
    const int c0 = (tid & 31) * 4;
    const int r0 = (tid >> 5) * 4;

    float acc[4][4];
#pragma unroll
    for (int j = 0; j < 4; ++j)
#pragma unroll
        for (int m = 0; m < 4; ++m) acc[j][m] = 0.f;

    for (int half = 0; half < 2; ++half) {
        const int kbase = half * 128;
        if (half) __syncthreads();
#pragma unroll
        for (int t = 0; t < 4; ++t) {
            int i = t * 256 + tid;
            int r = i >> 5;
            int q = i & 31;
            *((float4*)&xs[r][q * 4]) =
                *((const float4*)(x + (size_t)(row0 + r) * IN_F + kbase + q * 4));
        }
        __syncthreads();

#pragma unroll 4
        for (int kq = 0; kq < 128; kq += 4) {
            const float* wp = W + (size_t)(kbase + kq) * NCOL + c0;
            float4 w0 = *((const float4*)(wp));
            float4 w1 = *((const float4*)(wp + NCOL));
            float4 w2 = *((const float4*)(wp + 2 * NCOL));
            float4 w3 = *((const float4*)(wp + 3 * NCOL));
#pragma unroll
            for (int j = 0; j < 4; ++j) {
                float4 xv = *((const float4*)&xs[r0 + j][kq]);
                acc[j][0] += xv.x * w0.x + xv.y * w1.x + xv.z * w2.x + xv.w * w3.x;
                acc[j][1] += xv.x * w0.y + xv.y * w1.y + xv.z * w2.y + xv.w * w3.y;
                acc[j][2] += xv.x * w0.z + xv.y * w1.z + xv.z * w2.z + xv.w * w3.z;
                acc[j][3] += xv.x * w0.w + xv.y * w1.w + xv.z * w2.w + xv.w * w3.w;
            }
        }
    }

#pragma unroll
    for (int j = 0; j < 4; ++j) {
        int row = row0 + r0 + j;
        *((float4*)(h + (size_t)row * NCOL + c0)) =
            make_float4(acc[j][0], acc[j][1], acc[j][2], acc[j][3]);
    }
}

// ---------------- K2: el / er exact fp64 from x — NO cross-lane ops ----------
// block = 64 rows. Wlr in LDS (wave-uniform broadcast reads: sl = tid>>6).
// x staged in 4 quarter-tiles; per-thread register partials; one LDS
// transpose (aliased onto xs) replaces the 48-shfl butterflies.
__global__ __launch_bounds__(256) void k_scores(const float* __restrict__ x,
                                                const double* __restrict__ Wlr_t,
                                                const int* __restrict__ dst_idx,
                                                double* __restrict__ el,
                                                double* __restrict__ er_src,
                                                int* __restrict__ cnt) {
    __shared__ double wlds[8][IN_F];              // 16 KB
    __shared__ __align__(16) char smem[64 * 72 * 4];  // 18 KB: xs / red alias
    float (*xs)[72] = (float (*)[72])smem;
    double (*red)[34] = (double (*)[34])smem;     // 64 x 34 dbl = 17408 B

    const int tid = threadIdx.x;
    const int row0 = blockIdx.x * 64;
    const int row = tid & 63;       // 0..63
    const int sl = tid >> 6;        // 0..3, wave-uniform

    // stage Wlr (coalesced, 8 doubles/thread)
    for (int i = tid; i < 8 * IN_F; i += 256)
        wlds[i >> 8][i & 255] = Wlr_t[i];

    double part[8] = {0.0, 0.0, 0.0, 0.0, 0.0, 0.0, 0.0, 0.0};

    for (int qt = 0; qt < 4; ++qt) {
        __syncthreads();  // previous xs/red readers done
        // stage 64 rows x 64 k (quarter), coalesced, zero-fill OOB
#pragma unroll
        for (int t = 0; t < 4; ++t) {
            int i = t * 256 + tid;
            int r = i >> 4;       // 0..63
            int q = i & 15;       // float4 within quarter
            int rr = row0 + r;
            float4 v = make_float4(0.f, 0.f, 0.f, 0.f);
            if (rr < N_SRC)
                v = *((const float4*)(x + (size_t)rr * IN_F + qt * 64 + q * 4));
            *((float4*)&xs[r][q * 4]) = v;
        }
        __syncthreads();

        // this thread's 16-k slice of the quarter
        float4 xv0 = *((const float4*)&xs[row][sl * 16 + 0]);
        float4 xv1 = *((const float4*)&xs[row][sl * 16 + 4]);
        float4 xv2 = *((const float4*)&xs[row][sl * 16 + 8]);
        float4 xv3 = *((const float4*)&xs[row][sl * 16 + 12]);
        const int kb = qt * 64 + sl * 16;
#pragma unroll
        for (int j = 0; j < 8; ++j) {
            const double* wp = &wlds[j][kb];  // same addr across wave: broadcast
            part[j] += (double)xv0.x * wp[0]  + (double)xv0.y * wp[1]
                     + (double)xv0.z * wp[2]  + (double)xv0.w * wp[3]
                     + (double)xv1.x * wp[4]  + (double)xv1.y * wp[5]
                     + (double)xv1.z * wp[6]  + (double)xv1.w * wp[7]
                     + (double)xv2.x * wp[8]  + (double)xv2.y * wp[9]
                     + (double)xv2.z * wp[10] + (double)xv2.w * wp[11]
                     + (double)xv3.x * wp[12] + (double)xv3.y * wp[13]
                     + (double)xv3.z * wp[14] + (double)xv3.w * wp[15];
        }
    }

    // reduce the 4 slice-partials per (row, j) via LDS transpose
    __syncthreads();  // xs reads done; alias as red
#pragma unroll
    for (int j = 0; j < 8; ++j) red[row][sl * 8 + j] = part[j];
    __syncthreads();
    {
        int row2 = tid & 63;
        int hh = tid >> 6;  // 0..3
        if (row0 + row2 < N_SRC) {
            double s_l = red[row2][0 * 8 + hh] + red[row2][1 * 8 + hh]
                       + red[row2][2 * 8 + hh] + red[row2][3 * 8 + hh];
            double s_r = red[row2][0 * 8 + hh + 4] + red[row2][1 * 8 + hh + 4]
                       + red[row2][2 * 8 + hh + 4] + red[row2][3 * 8 + hh + 4];
            el[(size_t)(row0 + row2) * NH + hh] = s_l;
            er_src[(size_t)(row0 + row2) * NH + hh] = s_r;
        }
    }

    // histogram tail (cnt pre-zeroed by memset)
    for (int e = blockIdx.x * 256 + tid; e < NE; e += gridDim.x * 256)
        atomicAdd(cnt + dst_idx[e], 1);
}

// ---------------- k_scan: exclusive scan of cnt -> offsets; zero cursor ----
__global__ __launch_bounds__(1024) void k_scan(const int* __restrict__ cnt,
                                               int* __restrict__ offsets,
                                               int* __restrict__ cursor) {
    __shared__ int wsum[16];
    __shared__ int carry;
    int tid = threadIdx.x, lane = tid & 63, w = tid >> 6;
    if (tid == 0) carry = 0;
    __syncthreads();
    for (int base = 0; base < N_DST; base += 1024) {
        int i = base + tid;
        int v = (i < N_DST) ? cnt[i] : 0;
        int s = v;
#pragma unroll
        for (int off = 1; off < 64; off <<= 1) {
            int t = __shfl_up(s, off);
            if (lane >= off) s += t;
        }
        if (lane == 63) wsum[w] = s;
        __syncthreads();
        int wprefix = 0;
        for (int k = 0; k < w; ++k) wprefix += wsum[k];
        int incl = s + wprefix + carry;
        if (i < N_DST) {
            offsets[i + 1] = incl;
            cursor[i] = 0;
        }
        __syncthreads();
        if (tid == 1023) carry = incl;
        __syncthreads();
    }
    if (tid == 0) offsets[0] = 0;
}

__global__ __launch_bounds__(256) void k_fill(const int* __restrict__ src_idx,
                                              const int* __restrict__ dst_idx,
                                              const int* __restrict__ offsets,
                                              int* __restrict__ cursor,
                                              int* __restrict__ edge_src) {
    int gid = blockIdx.x * 256 + threadIdx.x;
    if (gid >= NE) return;
    int d = dst_idx[gid];
    int pos = offsets[d] + atomicAdd(cursor + d, 1);
    edge_src[pos] = src_idx[gid];
}

// ---------------- K5: fused S + normalize + weighted gather ----------------
// one WAVE per dst node (4 dst per 256-thread block); no barriers, no LDS.
__global__ __launch_bounds__(256) void k_fused(const int* __restrict__ offsets,
                                               const int* __restrict__ edge_src,
                                               const double* __restrict__ el,
                                               const double* __restrict__ er_src,
                                               const int* __restrict__ dst_to_src,
                                               const float* __restrict__ h,
                                               float* __restrict__ out) {
    const int lane = threadIdx.x & 63;
    const int d = blockIdx.x * 4 + (threadIdx.x >> 6);
    if (d >= N_DST) return;
    const int beg = offsets[d];
    const int deg = offsets[d + 1] - beg;

    const int srcd = dst_to_src[d];
    double er4[NH];
#pragma unroll
    for (int hh = 0; hh < NH; ++hh) er4[hh] = er_src[(size_t)srcd * NH + hh];

    // phase 1: S[h] via per-lane partial + wave butterfly (fp64)
    double sum4[NH] = {0.0, 0.0, 0.0, 0.0};
    for (int j = lane; j < deg; j += 64) {
        int s = edge_src[beg + j];
        const double* elp = el + (size_t)s * NH;
#pragma unroll
        for (int hh = 0; hh < NH; ++hh) {
            double e = elp[hh] + er4[hh];
            e = (e >= 0.0) ? e : 0.2 * e;
            sum4[hh] += e;
        }
    }
#pragma unroll
    for (int hh = 0; hh < NH; ++hh) {
#pragma unroll
        for (int m = 32; m >= 1; m >>= 1)
            sum4[hh] += __shfl_xor(sum4[hh], m);
    }

    // phase 2: 2 edges in flight; lane = (js, col quad cq)
    const int js = lane >> 5;
    const int cq = lane & 31;
    const int hd = cq >> 3;
    const double Sinv = (deg > 0) ? 1.0 / sum4[hd] : 0.0;

    double acc[4] = {0.0, 0.0, 0.0, 0.0};
    for (int j = js; j < deg; j += 2) {
        int s = edge_src[beg + j];
        double e = el[(size_t)s * NH + hd] + er4[hd];
        e = (e >= 0.0) ? e : 0.2 * e;
        double att = e * Sinv;
        float4 hv = *((const float4*)(h + (size_t)s * NCOL + cq * 4));
        acc[0] += att * (double)hv.x;
        acc[1] += att * (double)hv.y;
        acc[2] += att * (double)hv.z;
        acc[3] += att * (double)hv.w;
    }
#pragma unroll
    for (int m = 0; m < 4; ++m) acc[m] += __shfl_xor(acc[m], 32);

    if (lane < 32) {
        *((float4*)(out + (size_t)d * NCOL + lane * 4)) =
            make_float4((float)acc[0], (float)acc[1], (float)acc[2], (float)acc[3]);
    }
}

extern "C" void kernel_launch(void* const* d_in, const int* in_sizes, int n_in,
                              void* d_out, int out_size, void* d_ws, size_t ws_size,
                              hipStream_t stream) {
    const float* x      = (const float*)d_in[0];
    const float* W      = (const float*)d_in[1];
    const float* attn_l = (const float*)d_in[2];
    const float* attn_r = (const float*)d_in[3];
    const int* src_idx  = (const int*)d_in[4];
    const int* dst_idx  = (const int*)d_in[5];
    const int* dst_to_src = (const int*)d_in[6];
    float* out = (float*)d_out;

    char* p = (char*)d_ws;
    double* Wlr_t  = (double*)p;  p += (size_t)8 * IN_F * sizeof(double);     // 16 KB
    double* el     = (double*)p;  p += (size_t)N_SRC * NH * sizeof(double);   // 3.2 MB
    double* er_src = (double*)p;  p += (size_t)N_SRC * NH * sizeof(double);   // 3.2 MB
    float*  h      = (float*)p;   p += (size_t)N_SRC * NCOL * sizeof(float);  // 51.2 MB
    int*    cnt      = (int*)p;   p += (size_t)N_DST * sizeof(int);
    int*    offsets  = (int*)p;   p += (size_t)(N_DST + 1) * sizeof(int);
    int*    cursor   = (int*)p;   p += (size_t)N_DST * sizeof(int);
    int*    edge_src = (int*)p;   p += (size_t)NE * sizeof(int);

    hipMemsetAsync(cnt, 0, (size_t)N_DST * sizeof(int), stream);

    k_prep<<<1, 256, 0, stream>>>(W, attn_l, attn_r, Wlr_t);
    k_gemm<<<N_SRC / 32, 256, 0, stream>>>(x, W, h);
    k_scores<<<(N_SRC + 63) / 64, 256, 0, stream>>>(x, Wlr_t, dst_idx, el, er_src, cnt);
    k_scan<<<1, 1024, 0, stream>>>(cnt, offsets, cursor);
    k_fill<<<(NE + 255) / 256, 256, 0, stream>>>(src_idx, dst_idx, offsets, cursor, edge_src);
    k_fused<<<N_DST / 4, 256, 0, stream>>>(offsets, edge_src, el, er_src, dst_to_src, h, out);
}

// Round 11
// 292.306 us; speedup vs baseline: 2.2758x; 1.0667x over previous
//
#include <hip/hip_runtime.h>

#define N_SRC 100000
#define N_DST 20000
#define NE 640000
#define IN_F 256
#define NH 4
#define DF 32
#define NCOL 128  /* NH*DF */

// ---------------- K0: fold attn vectors into W (fp64) ----------------
// Wlr_t[j][k] = sum_d W[k][(j&3)*32+d] * attn_{l:j<4, r:j>=4}[(j&3)*32+d]
__global__ void k_prep(const float* __restrict__ W,
                       const float* __restrict__ attn_l,
                       const float* __restrict__ attn_r,
                       double* __restrict__ Wlr_t) {
    int k = threadIdx.x;  // 256 threads
    for (int j = 0; j < 8; ++j) {
        const float* attn = (j < 4) ? attn_l : attn_r;
        int hh = j & 3;
        double s = 0.0;
        for (int d = 0; d < DF; ++d)
            s += (double)W[k * NCOL + hh * DF + d] * (double)attn[hh * DF + d];
        Wlr_t[(size_t)j * IN_F + k] = s;
    }
}

// ---------------- K1: h = x @ W (fp32) + exact fp64 scores + histogram ------
// 32-row tile, two 128-k halves. xs padded to [32][132] (score reads
// conflict-free); wlds padded to [8][258]. Score thread-mapping
// (srow=tid>>3, sj=tid&7) = 32x8 outputs, zero cross-thread reduction.
// GEMM k-order unchanged -> h bit-identical. Scores are fp64 from staged
// x values (float->double exact) -> same numerics class as rounds 2-8.
// N_SRC = 3125*32 exactly -> no bounds checks.
__global__ __launch_bounds__(256) void k_gemm(const float* __restrict__ x,
                                              const float* __restrict__ W,
                                              const double* __restrict__ Wlr_t,
                                              const int* __restrict__ dst_idx,
                                              float* __restrict__ h,
                                              double* __restrict__ el,
                                              double* __restrict__ er_src,
                                              int* __restrict__ cnt) {
    __shared__ float xs[32][132];    // 16.9 KB (pad 132: +4 banks/row)
    __shared__ double wlds[8][258];  // 16.5 KB (pad 258: +4 banks/row)
    const int tid = threadIdx.x;
    const int row0 = blockIdx.x * 32;
    const int c0 = (tid & 31) * 4;   // gemm: 4 consecutive cols
    const int r0 = (tid >> 5) * 4;   // gemm: 4 consecutive rows
    const int srow = tid >> 3;       // score: row 0..31
    const int sj = tid & 7;          // score: output 0..7 (l:0-3, r:4-7)

    // stage Wlr (one-time; covered by the first __syncthreads below)
    for (int i = tid; i < 8 * IN_F; i += 256)
        wlds[i >> 8][i & 255] = Wlr_t[i];

    float acc[4][4];
#pragma unroll
    for (int j = 0; j < 4; ++j)
#pragma unroll
        for (int m = 0; m < 4; ++m) acc[j][m] = 0.f;
    double sacc = 0.0;

    for (int half = 0; half < 2; ++half) {
        const int kbase = half * 128;
        if (half) __syncthreads();  // all xs readers of prev half done
        // stage 32 rows x 128 k, coalesced
#pragma unroll
        for (int t = 0; t < 4; ++t) {
            int i = t * 256 + tid;
            int r = i >> 5;
            int q = i & 31;
            *((float4*)&xs[r][q * 4]) =
                *((const float4*)(x + (size_t)(row0 + r) * IN_F + kbase + q * 4));
        }
        __syncthreads();

        // ---- GEMM inner (unchanged math/order) ----
#pragma unroll 4
        for (int kq = 0; kq < 128; kq += 4) {
            const float* wp = W + (size_t)(kbase + kq) * NCOL + c0;
            float4 w0 = *((const float4*)(wp));
            float4 w1 = *((const float4*)(wp + NCOL));
            float4 w2 = *((const float4*)(wp + 2 * NCOL));
            float4 w3 = *((const float4*)(wp + 3 * NCOL));
#pragma unroll
            for (int j = 0; j < 4; ++j) {
                float4 xv = *((const float4*)&xs[r0 + j][kq]);
                acc[j][0] += xv.x * w0.x + xv.y * w1.x + xv.z * w2.x + xv.w * w3.x;
                acc[j][1] += xv.x * w0.y + xv.y * w1.y + xv.z * w2.y + xv.w * w3.y;
                acc[j][2] += xv.x * w0.z + xv.y * w1.z + xv.z * w2.z + xv.w * w3.z;
                acc[j][3] += xv.x * w0.w + xv.y * w1.w + xv.z * w2.w + xv.w * w3.w;
            }
        }

        // ---- score inner: sacc += dot(x[srow][kbase..], Wlr[sj][kbase..]) ----
        {
            const double* wp = &wlds[sj][kbase];
#pragma unroll 4
            for (int k = 0; k < 128; k += 4) {
                float4 xv = *((const float4*)&xs[srow][k]);
                double2 wa = *((const double2*)(wp + k));
                double2 wb = *((const double2*)(wp + k + 2));
                sacc += (double)xv.x * wa.x + (double)xv.y * wa.y
                      + (double)xv.z * wb.x + (double)xv.w * wb.y;
            }
        }
    }

    // write h
#pragma unroll
    for (int j = 0; j < 4; ++j) {
        int row = row0 + r0 + j;
        *((float4*)(h + (size_t)row * NCOL + c0)) =
            make_float4(acc[j][0], acc[j][1], acc[j][2], acc[j][3]);
    }

    // write scores
    {
        int row = row0 + srow;
        if (sj < 4) el[(size_t)row * NH + sj] = sacc;
        else        er_src[(size_t)row * NH + (sj - 4)] = sacc;
    }

    // histogram tail (cnt pre-zeroed by memset)
    for (int e = blockIdx.x * 256 + tid; e < NE; e += gridDim.x * 256)
        atomicAdd(cnt + dst_idx[e], 1);
}

// ---------------- k_scan: exclusive scan of cnt -> offsets; zero cursor ----
__global__ __launch_bounds__(1024) void k_scan(const int* __restrict__ cnt,
                                               int* __restrict__ offsets,
                                               int* __restrict__ cursor) {
    __shared__ int wsum[16];
    __shared__ int carry;
    int tid = threadIdx.x, lane = tid & 63, w = tid >> 6;
    if (tid == 0) carry = 0;
    __syncthreads();
    for (int base = 0; base < N_DST; base += 1024) {
        int i = base + tid;
        int v = (i < N_DST) ? cnt[i] : 0;
        int s = v;
#pragma unroll
        for (int off = 1; off < 64; off <<= 1) {
            int t = __shfl_up(s, off);
            if (lane >= off) s += t;
        }
        if (lane == 63) wsum[w] = s;
        __syncthreads();
        int wprefix = 0;
        for (int k = 0; k < w; ++k) wprefix += wsum[k];
        int incl = s + wprefix + carry;
        if (i < N_DST) {
            offsets[i + 1] = incl;
            cursor[i] = 0;
        }
        __syncthreads();
        if (tid == 1023) carry = incl;
        __syncthreads();
    }
    if (tid == 0) offsets[0] = 0;
}

__global__ __launch_bounds__(256) void k_fill(const int* __restrict__ src_idx,
                                              const int* __restrict__ dst_idx,
                                              const int* __restrict__ offsets,
                                              int* __restrict__ cursor,
                                              int* __restrict__ edge_src) {
    int gid = blockIdx.x * 256 + threadIdx.x;
    if (gid >= NE) return;
    int d = dst_idx[gid];
    int pos = offsets[d] + atomicAdd(cursor + d, 1);
    edge_src[pos] = src_idx[gid];
}

// ---------------- K5: fused S + normalize + weighted gather ----------------
// one WAVE per dst node (4 dst per 256-thread block); no barriers, no LDS.
__global__ __launch_bounds__(256) void k_fused(const int* __restrict__ offsets,
                                               const int* __restrict__ edge_src,
                                               const double* __restrict__ el,
                                               const double* __restrict__ er_src,
                                               const int* __restrict__ dst_to_src,
                                               const float* __restrict__ h,
                                               float* __restrict__ out) {
    const int lane = threadIdx.x & 63;
    const int d = blockIdx.x * 4 + (threadIdx.x >> 6);
    if (d >= N_DST) return;
    const int beg = offsets[d];
    const int deg = offsets[d + 1] - beg;

    const int srcd = dst_to_src[d];
    double er4[NH];
#pragma unroll
    for (int hh = 0; hh < NH; ++hh) er4[hh] = er_src[(size_t)srcd * NH + hh];

    // phase 1: S[h] via per-lane partial + wave butterfly (fp64)
    double sum4[NH] = {0.0, 0.0, 0.0, 0.0};
    for (int j = lane; j < deg; j += 64) {
        int s = edge_src[beg + j];
        const double* elp = el + (size_t)s * NH;
#pragma unroll
        for (int hh = 0; hh < NH; ++hh) {
            double e = elp[hh] + er4[hh];
            e = (e >= 0.0) ? e : 0.2 * e;
            sum4[hh] += e;
        }
    }
#pragma unroll
    for (int hh = 0; hh < NH; ++hh) {
#pragma unroll
        for (int m = 32; m >= 1; m >>= 1)
            sum4[hh] += __shfl_xor(sum4[hh], m);
    }

    // phase 2: 2 edges in flight; lane = (js, col quad cq)
    const int js = lane >> 5;
    const int cq = lane & 31;
    const int hd = cq >> 3;
    const double Sinv = (deg > 0) ? 1.0 / sum4[hd] : 0.0;

    double acc[4] = {0.0, 0.0, 0.0, 0.0};
    for (int j = js; j < deg; j += 2) {
        int s = edge_src[beg + j];
        double e = el[(size_t)s * NH + hd] + er4[hd];
        e = (e >= 0.0) ? e : 0.2 * e;
        double att = e * Sinv;
        float4 hv = *((const float4*)(h + (size_t)s * NCOL + cq * 4));
        acc[0] += att * (double)hv.x;
        acc[1] += att * (double)hv.y;
        acc[2] += att * (double)hv.z;
        acc[3] += att * (double)hv.w;
    }
#pragma unroll
    for (int m = 0; m < 4; ++m) acc[m] += __shfl_xor(acc[m], 32);

    if (lane < 32) {
        *((float4*)(out + (size_t)d * NCOL + lane * 4)) =
            make_float4((float)acc[0], (float)acc[1], (float)acc[2], (float)acc[3]);
    }
}

extern "C" void kernel_launch(void* const* d_in, const int* in_sizes, int n_in,
                              void* d_out, int out_size, void* d_ws, size_t ws_size,
                              hipStream_t stream) {
    const float* x      = (const float*)d_in[0];
    const float* W      = (const float*)d_in[1];
    const float* attn_l = (const float*)d_in[2];
    const float* attn_r = (const float*)d_in[3];
    const int* src_idx  = (const int*)d_in[4];
    const int* dst_idx  = (const int*)d_in[5];
    const int* dst_to_src = (const int*)d_in[6];
    float* out = (float*)d_out;

    char* p = (char*)d_ws;
    double* Wlr_t  = (double*)p;  p += (size_t)8 * IN_F * sizeof(double);     // 16 KB
    double* el     = (double*)p;  p += (size_t)N_SRC * NH * sizeof(double);   // 3.2 MB
    double* er_src = (double*)p;  p += (size_t)N_SRC * NH * sizeof(double);   // 3.2 MB
    float*  h      = (float*)p;   p += (size_t)N_SRC * NCOL * sizeof(float);  // 51.2 MB
    int*    cnt      = (int*)p;   p += (size_t)N_DST * sizeof(int);
    int*    offsets  = (int*)p;   p += (size_t)(N_DST + 1) * sizeof(int);
    int*    cursor   = (int*)p;   p += (size_t)N_DST * sizeof(int);
    int*    edge_src = (int*)p;   p += (size_t)NE * sizeof(int);

    hipMemsetAsync(cnt, 0, (size_t)N_DST * sizeof(int), stream);

    k_prep<<<1, 256, 0, stream>>>(W, attn_l, attn_r, Wlr_t);
    k_gemm<<<N_SRC / 32, 256, 0, stream>>>(x, W, Wlr_t, dst_idx, h, el, er_src, cnt);
    k_scan<<<1, 1024, 0, stream>>>(cnt, offsets, cursor);
    k_fill<<<(NE + 255) / 256, 256, 0, stream>>>(src_idx, dst_idx, offsets, cursor, edge_src);
    k_fused<<<N_DST / 4, 256, 0, stream>>>(offsets, edge_src, el, er_src, dst_to_src, h, out);
}